// Round 13
// baseline (137.803 us; speedup 1.0000x reference)
//
#include <hip/hip_runtime.h>

#define BB 4
#define TT 1024
#define DD 128
#define LL 32   // chunk length
#define CC 32   // TT/LL
#define EPSV 1e-6f

#define BTD (BB*TT*DD)
#define BCD (BB*CC*DD)

// workspace offsets (floats)
#define OFF_QC   0                  // relu(q) -> qc (in-place)
#define OFF_KH   (OFF_QC + BTD)     // relu(k) -> kh (in-place)
#define OFF_V    (OFF_KH + BTD)
#define OFF_G    (OFF_V  + BTD)     // sigmoid(a)
#define OFF_CL   (OFF_G  + BTD)
#define OFF_KS   (OFF_CL + BCD)
#define OFF_Z0   (OFF_KS + BCD)
#define OFF_U    (OFF_Z0 + BCD)     // [B][C][D][D]  (8.4 MB)
#define OFF_S0   (OFF_U  + BB*CC*DD*DD)

// ---------------------------------------------------------------------------
// Kernel 1 (proven R11): fused 4-projection GEMM, 64x64 tile, 4x4 acc.
// ---------------------------------------------------------------------------
__global__ __launch_bounds__(256) void k_gemm(
    const float* __restrict__ x,
    const float* __restrict__ Wq, const float* __restrict__ bq,
    const float* __restrict__ Wk, const float* __restrict__ bk,
    const float* __restrict__ Wv, const float* __restrict__ bv,
    const float* __restrict__ Wa, const float* __restrict__ ba,
    float* __restrict__ ws)
{
    __shared__ float xs [64][DD];
    __shared__ float wsh[64][132];

    const int tid = threadIdx.x;
    const int bx  = blockIdx.x;
    const int rt  = bx >> 3;
    const int mt  = bx & 7;
    const int m   = mt >> 1;
    const int jh  = mt & 1;

    const float* W    = (m==0)?Wq : (m==1)?Wk : (m==2)?Wv : Wa;
    const float* bias = (m==0)?bq : (m==1)?bk : (m==2)?bv : ba;

    {
        const float4* xg = (const float4*)(x + (size_t)rt*64*DD);
        const float4* wg = (const float4*)(W + (size_t)jh*64*DD);
        #pragma unroll
        for (int r=0;r<8;r++){
            int f = tid + r*256;
            *(float4*)&xs [f>>5][(f&31)*4] = xg[f];
            *(float4*)&wsh[f>>5][(f&31)*4] = wg[f];
        }
    }
    __syncthreads();

    const int ci = tid & 15;
    const int ri = tid >> 4;

    float acc[4][4];
    #pragma unroll
    for (int cc=0;cc<4;cc++){
        float bv_ = bias[jh*64 + ci + 16*cc];
        #pragma unroll
        for (int rr=0;rr<4;rr++) acc[rr][cc]=bv_;
    }

    #pragma unroll 2
    for (int k4=0; k4<32; k4++){
        float4 xa0 = *(const float4*)&xs[ri     ][k4*4];
        float4 xa1 = *(const float4*)&xs[ri + 16][k4*4];
        float4 xa2 = *(const float4*)&xs[ri + 32][k4*4];
        float4 xa3 = *(const float4*)&xs[ri + 48][k4*4];
        #pragma unroll
        for (int cc=0;cc<4;cc++){
            float4 w = *(const float4*)&wsh[ci+16*cc][k4*4];
            acc[0][cc] = fmaf(xa0.x,w.x, fmaf(xa0.y,w.y, fmaf(xa0.z,w.z, fmaf(xa0.w,w.w, acc[0][cc]))));
            acc[1][cc] = fmaf(xa1.x,w.x, fmaf(xa1.y,w.y, fmaf(xa1.z,w.z, fmaf(xa1.w,w.w, acc[1][cc]))));
            acc[2][cc] = fmaf(xa2.x,w.x, fmaf(xa2.y,w.y, fmaf(xa2.z,w.z, fmaf(xa2.w,w.w, acc[2][cc]))));
            acc[3][cc] = fmaf(xa3.x,w.x, fmaf(xa3.y,w.y, fmaf(xa3.z,w.z, fmaf(xa3.w,w.w, acc[3][cc]))));
        }
    }

    float* dst = ws + ((m==0)?OFF_QC : (m==1)?OFF_KH : (m==2)?OFF_V : OFF_G);
    #pragma unroll
    for (int rr=0;rr<4;rr++){
        int row = rt*64 + ri + 16*rr;
        #pragma unroll
        for (int cc=0;cc<4;cc++){
            float v = acc[rr][cc];
            if (m==0 || m==1) v = fmaxf(v, 0.f);
            else if (m==3)    v = 1.f/(1.f+__expf(-v));
            dst[(size_t)row*DD + jh*64 + ci + 16*cc] = v;
        }
    }
}

// ---------------------------------------------------------------------------
// Kernel 2 (proven, unchanged): per (chunk, i-quarter) postprocess + U.
// ---------------------------------------------------------------------------
__global__ __launch_bounds__(256) void k_chunk(float* __restrict__ ws)
{
    __shared__ float qs [LL][32];
    __shared__ float krs[LL][32];
    __shared__ float gs [LL][32];
    __shared__ float vs [LL][DD];
    __shared__ float kbs[LL][32];

    const int tid = threadIdx.x;
    const int bq_ = blockIdx.x;        // bc*4 + q
    const int bc  = bq_ >> 2;
    const int iq  = bq_ & 3;
    const int ibase = iq*32;
    const int b   = bc / CC;
    const int t0  = (bc % CC) * LL;
    const size_t tile = (size_t)(b*TT + t0)*DD;

    {
        const int t = tid >> 3, c4 = (tid & 7)*4;
        const size_t off = tile + (size_t)t*DD + ibase + c4;
        *(float4*)&qs [t][c4] = *(const float4*)(ws + OFF_QC + off);
        *(float4*)&krs[t][c4] = *(const float4*)(ws + OFF_KH + off);
        *(float4*)&gs [t][c4] = *(const float4*)(ws + OFF_G  + off);
        #pragma unroll
        for (int r=0;r<4;r++){
            int f = tid + r*256;
            int tv = f >> 5, cv = (f & 31)*4;
            *(float4*)&vs[tv][cv] = *(const float4*)(ws + OFF_V + tile + (size_t)tv*DD + cv);
        }
    }
    __syncthreads();

    if (tid < 32){
        float c = 1.f;
        #pragma unroll
        for (int t=0;t<LL;t++){ c *= gs[t][tid]; gs[t][tid] = c; }
        ws[OFF_CL + (size_t)bc*DD + ibase + tid] = c;
    }
    __syncthreads();

    {
        const int col = tid & 31;
        const int tg  = tid >> 5;
        const float cl = gs[LL-1][col];
        #pragma unroll
        for (int r=0;r<4;r++){
            int t = tg*4 + r;
            float cv = gs[t][col];
            ws[OFF_QC + tile + (size_t)t*DD + ibase + col] = qs[t][col] * cv;
            float kh = krs[t][col] / cv;
            ws[OFF_KH + tile + (size_t)t*DD + ibase + col] = kh;
            kbs[t][col] = kh * cl;
        }
    }
    __syncthreads();

    if (tid < 32){
        float s = 0.f;
        #pragma unroll
        for (int t=0;t<LL;t++) s += kbs[t][tid];
        ws[OFF_KS + (size_t)bc*DD + ibase + tid] = s;
    }

    const int j  = tid & 127;
    const int ih = tid >> 7;
    float vr[LL];
    #pragma unroll
    for (int u=0;u<LL;u++) vr[u]=vs[u][j];
    float* Ug = ws + OFF_U + (size_t)bc*DD*DD;
    #pragma unroll
    for (int i4=0;i4<4;i4++){
        int il = ih*16 + i4*4;
        float a0=0.f,a1=0.f,a2=0.f,a3=0.f;
        #pragma unroll
        for (int u=0;u<LL;u++){
            float4 kb4 = *(const float4*)(&kbs[u][il]);
            float vu = vr[u];
            a0 = fmaf(kb4.x,vu,a0); a1 = fmaf(kb4.y,vu,a1);
            a2 = fmaf(kb4.z,vu,a2); a3 = fmaf(kb4.w,vu,a3);
        }
        Ug[(size_t)(ibase+il+0)*DD + j]=a0; Ug[(size_t)(ibase+il+1)*DD + j]=a1;
        Ug[(size_t)(ibase+il+2)*DD + j]=a2; Ug[(size_t)(ibase+il+3)*DD + j]=a3;
    }
}

// ---------------------------------------------------------------------------
// Kernel 3 (proven, unchanged): per-element scan, CC=32, 16-deep ring.
// ---------------------------------------------------------------------------
__global__ __launch_bounds__(128) void k_scan(float* __restrict__ ws)
{
    __shared__ float cls[CC], kss[CC];
    const int bi = blockIdx.x;
    const int b  = bi >> 7;
    const int i  = bi & 127;
    const int j  = threadIdx.x;

    if (j < CC)        cls[j]      = ws[OFF_CL + (size_t)(b*CC + j)*DD + i];
    else if (j < 2*CC) kss[j - CC] = ws[OFF_KS + (size_t)(b*CC + j - CC)*DD + i];
    __syncthreads();

    const float* U  = ws + OFF_U;
    float*       s0 = ws + OFF_S0;
    float*       z0 = ws + OFF_Z0;
    const size_t base = (size_t)b*CC*DD*DD + (size_t)i*DD + j;

    float up[16];
    #pragma unroll
    for (int p=0;p<16;p++) up[p] = U[base + (size_t)p*DD*DD];

    float s = 0.f, z = 0.f;
    #pragma unroll
    for (int ch=0; ch<CC; ch++){
        s0[base + (size_t)ch*DD*DD] = s;
        if (j==0) z0[(size_t)(b*CC+ch)*DD + i] = z;
        float u  = up[ch & 15];
        if (ch + 16 < CC) up[ch & 15] = U[base + (size_t)(ch+16)*DD*DD];
        float cl = cls[ch];
        s = fmaf(cl, s, u);
        z = fmaf(cl, z, kss[ch]);
    }
}

// ---------------------------------------------------------------------------
// Kernel 4 v3: per (chunk, t-half) output, FULL j width, 512 threads.
// 256 blocks, ~62KB LDS -> 1 block/CU, 8 waves/CU (same as before), but
// kh staged x2 (was x4) and qc x1 (was x2): -12.6 MB traffic.
// ---------------------------------------------------------------------------
__global__ __launch_bounds__(512) void k_out(const float* __restrict__ ws, float* __restrict__ y)
{
    __shared__ float khs[LL][DD+4];     // all u rows           16.9 KB
    __shared__ float qcs[16][DD+4];     // own t rows            8.4 KB
    __shared__ float vsm[LL][DD+4];     // all u x full j       16.9 KB
    __shared__ float s0s[32][DD+4];     // staged s0 slice      16.9 KB
    __shared__ float Ss[16][LL];        //                       2.0 KB
    __shared__ float denS[16];
    __shared__ float z0s[DD];

    const int tid = threadIdx.x;
    const int blk = blockIdx.x;        // bc*2 + th
    const int bc  = blk >> 1;
    const int th  = blk & 1;
    const int tbase = th * 16;
    const int b   = bc / CC;
    const int ch  = bc % CC;
    const int t0  = ch * LL;
    const size_t tile = (size_t)(b*TT + t0)*DD;
    const float* s0g = ws + OFF_S0 + (size_t)bc*DD*DD;

    float4 pre[2];
    {   // kh full (1024 f4), v full (1024 f4), qc own t-half (512 f4)
        const float4* khg = (const float4*)(ws + OFF_KH + tile);
        const float4* vg  = (const float4*)(ws + OFF_V  + tile);
        #pragma unroll
        for (int r=0;r<2;r++){
            int f = tid + r*512;
            int t = f >> 5, k4 = f & 31;
            *(float4*)&khs[t][k4*4] = khg[f];
            *(float4*)&vsm[t][k4*4] = vg [f];
        }
        if (tid < 512){
            int f = tid;
            int t = f >> 5, k4 = f & 31;
            const float4* qcg = (const float4*)(ws + OFF_QC + tile + (size_t)tbase*DD);
            *(float4*)&qcs[t][k4*4] = qcg[f];
        }
        if (tid < DD) z0s[tid] = ws[OFF_Z0 + (size_t)bc*DD + tid];
        // prefetch slice 0 of s0 (32 i-rows x 128 j = 1024 f4, 2/thread)
        #pragma unroll
        for (int r=0;r<2;r++){
            int f = tid + r*512;
            pre[r] = ((const float4*)s0g)[f];
        }
    }
    __syncthreads();

    // scores: thread -> (tl = tid>>5, u = tid&31); one score each
    {
        const int tl = tid >> 5;
        const int u  = tid & 31;
        const int tg = tbase + tl;
        float s = 0.f;
        #pragma unroll 8
        for (int k4=0; k4<32; k4++){
            float4 q4 = *(const float4*)&qcs[tl][k4*4];
            float4 h4 = *(const float4*)&khs[u][k4*4];
            s = fmaf(q4.x,h4.x, fmaf(q4.y,h4.y, fmaf(q4.z,h4.z, fmaf(q4.w,h4.w, s))));
        }
        Ss[tl][u] = (u <= tg) ? s : 0.f;
    }
    __syncthreads();

    if (tid < 16){
        int tl = tid;
        float d = EPSV;
        #pragma unroll
        for (int u=0; u<LL; u++) d += Ss[tl][u];
        #pragma unroll 8
        for (int kk=0; kk<DD; kk++) d += qcs[tl][kk]*z0s[kk];
        denS[tl] = d;
    }

    const int tl = tid >> 5;
    const int j0 = (tid & 31) * 4;     // full 128-col width
    float y4[4] = {0.f,0.f,0.f,0.f};

    __syncthreads();
    // intra-chunk: S @ V
    #pragma unroll 8
    for (int u=0; u<LL; u++){
        float sv = Ss[tl][u];
        float4 v4 = *(const float4*)&vsm[u][j0];
        y4[0]=fmaf(sv,v4.x,y4[0]); y4[1]=fmaf(sv,v4.y,y4[1]);
        y4[2]=fmaf(sv,v4.z,y4[2]); y4[3]=fmaf(sv,v4.w,y4[3]);
    }

    // inter-chunk: qc @ s0, 4 slices of 32 i-rows, register double-buffer
    for (int sl=0; sl<4; sl++){
        __syncthreads();
        #pragma unroll
        for (int r=0;r<2;r++){
            int f = tid + r*512;
            *(float4*)&s0s[f>>5][(f&31)*4] = pre[r];
        }
        if (sl < 3){
            const float4* sg = (const float4*)(s0g + (size_t)(sl+1)*32*DD);
            #pragma unroll
            for (int r=0;r<2;r++) pre[r] = sg[tid + r*512];
        }
        __syncthreads();
        #pragma unroll 8
        for (int ii=0; ii<32; ii++){
            float qv = qcs[tl][sl*32+ii];
            float4 s4 = *(const float4*)&s0s[ii][j0];
            y4[0]=fmaf(qv,s4.x,y4[0]); y4[1]=fmaf(qv,s4.y,y4[1]);
            y4[2]=fmaf(qv,s4.z,y4[2]); y4[3]=fmaf(qv,s4.w,y4[3]);
        }
    }

    const float rd = 1.f/denS[tl];
    float* yg = y + tile + (size_t)(tbase + tl)*DD + j0;
    *(float4*)yg = make_float4(y4[0]*rd, y4[1]*rd, y4[2]*rd, y4[3]*rd);
}

extern "C" void kernel_launch(void* const* d_in, const int* in_sizes, int n_in,
                              void* d_out, int out_size, void* d_ws, size_t ws_size,
                              hipStream_t stream)
{
    const float* x  = (const float*)d_in[0];
    const float* Wq = (const float*)d_in[1]; const float* bq = (const float*)d_in[2];
    const float* Wk = (const float*)d_in[3]; const float* bk = (const float*)d_in[4];
    const float* Wv = (const float*)d_in[5]; const float* bv = (const float*)d_in[6];
    const float* Wa = (const float*)d_in[7]; const float* ba = (const float*)d_in[8];
    float* ws = (float*)d_ws;
    float* yo = (float*)d_out;

    hipLaunchKernelGGL(k_gemm,  dim3(512),     dim3(256), 0, stream,
                       x, Wq,bq, Wk,bk, Wv,bv, Wa,ba, ws);
    hipLaunchKernelGGL(k_chunk, dim3(BB*CC*4), dim3(256), 0, stream, ws);
    hipLaunchKernelGGL(k_scan,  dim3(BB*DD),   dim3(128), 0, stream, ws);
    hipLaunchKernelGGL(k_out,   dim3(BB*CC*2), dim3(512), 0, stream, ws, yo);
}